// Round 1
// 288.906 us; speedup vs baseline: 1.0499x; 1.0499x over previous
//
#include <hip/hip_runtime.h>
#include <hip/hip_bf16.h>

typedef __attribute__((ext_vector_type(8))) short short8;
typedef __attribute__((ext_vector_type(4))) float f32x4;
typedef __attribute__((ext_vector_type(4))) unsigned int u32x4;
typedef unsigned short u16;
typedef __attribute__((address_space(1))) void gvoid;
typedef __attribute__((address_space(3))) void lvoid;

static constexpr int BATCH = 8;
static constexpr int NDIM  = 2048;
static constexpr int MDIM  = 2048;
static constexpr int EDIM  = 1024;

// ---------------- phase 1: fp32 -> bf16 (RNE) ----------------
__device__ __forceinline__ unsigned bf16rne_pair(float a, float b) {
  unsigned ua = __float_as_uint(a), ub = __float_as_uint(b);
  ua = (ua + 0x7FFFu + ((ua >> 16) & 1u)) >> 16;
  ub = (ub + 0x7FFFu + ((ub >> 16) & 1u)) >> 16;
  return ua | (ub << 16);
}

__global__ __launch_bounds__(256)
void cvt_kernel(const float* __restrict__ A, const float* __restrict__ B,
                u16* __restrict__ Abf, u16* __restrict__ Bbf) {
  const int half = (BATCH * NDIM * EDIM) / (256 * 8);  // 8192 blocks per matrix
  int bid = blockIdx.x;
  const float* src; u16* dst;
  if (bid < half) { src = A; dst = Abf; }
  else            { src = B; dst = Bbf; bid -= half; }
  size_t idx = ((size_t)bid * 256 + threadIdx.x) * 8;
  f32x4 x = *(const f32x4*)(src + idx);
  f32x4 y = *(const f32x4*)(src + idx + 4);
  u32x4 r;
  r[0] = bf16rne_pair(x[0], x[1]);
  r[1] = bf16rne_pair(x[2], x[3]);
  r[2] = bf16rne_pair(y[0], y[1]);
  r[3] = bf16rne_pair(y[2], y[3]);
  *(u32x4*)(dst + idx) = r;
}

// ---------------- phase 2: 256x256 8-phase bf16 GEMM (T2+T3+T4+T5) ----------------
__device__ __forceinline__ void async_cp16(const void* g, void* l) {
  __builtin_amdgcn_global_load_lds((gvoid*)g, (lvoid*)l, 16, 0, 0);
}

#define BAR() do { asm volatile("" ::: "memory"); \
                   __builtin_amdgcn_s_barrier(); \
                   asm volatile("" ::: "memory"); } while (0)
#define WAITVM(N) asm volatile("s_waitcnt vmcnt(" #N ")" ::: "memory")

static constexpr int BM = 256;
static constexpr int BN = 256;
static constexpr int BK = 64;
static constexpr int KTILES = EDIM / BK;  // 16

__global__ __launch_bounds__(512, 2)
void bmm_8ph_kernel(const u16* __restrict__ A, const u16* __restrict__ B,
                    float* __restrict__ C) {
  // [buf][A=0/B=1][256 rows x 64 cols], XOR-swizzled at 16B-chunk granularity:
  // LDS[r][chunk c] holds global chunk (r, c ^ (r&7)).  128 KiB total.
  __shared__ u16 sh[2][2][BM * BK];

  const int tid  = threadIdx.x;
  const int lane = tid & 63;
  const int wave = tid >> 6;      // 0..7
  const int wr   = wave >> 2;     // 0..1  (wave-row: 128-row slab)
  const int wc   = wave & 3;      // 0..3  (wave-col: 64-col slab)
  const int quad = lane >> 4;
  const int ml   = lane & 15;

  const int tcol  = blockIdx.x;
  const int trow  = blockIdx.y;
  const int batch = blockIdx.z;

  const u16* Ab = A + (size_t)batch * NDIM * EDIM + (size_t)trow * BM * EDIM;
  const u16* Bb = B + (size_t)batch * MDIM * EDIM + (size_t)tcol * BN * EDIM;

  // ---- staging addressing (pre-swizzled global source; linear LDS dest) ----
  // half-tile = 128 rows x 64 cols.  instr j in {0,1}: linear chunk L = j*512+tid,
  // row r = L>>3, chunk c = L&7.  Lane fetches global chunk (r, c ^ (r&7)).
  const int r0 = tid >> 3;                     // 0..63 (j adds 64)
  const int cs = (tid & 7) ^ (r0 & 7);         // (64 mod 8 == 0 -> same for j=1)
  const u16* gA = Ab + (size_t)r0 * EDIM + cs * 8;
  const u16* gB = Bb + (size_t)r0 * EDIM + cs * 8;

  // STG(buf, ab, h, gptr, t): stage half-tile h (rows h*128..h*128+127) of
  // K-tile t into sh[buf][ab].  2 x global_load_lds (16B) per thread.
  // LDS base is wave-uniform; HW adds lane*16.
#define STG(buf, ab, h, gptr, t) do {                                          \
    const u16* _g = (gptr) + (size_t)((h) * 128) * EDIM + (size_t)(t) * BK;    \
    async_cp16(_g,                   &sh[buf][ab][(h) * 8192 + wave * 512]);   \
    async_cp16(_g + (size_t)64 * EDIM,                                         \
               &sh[buf][ab][(h) * 8192 + 4096 + wave * 512]);                  \
  } while (0)

  // ---- ds_read fragment addressing (swizzled) ----
  // element = row*64 + ((ks*4 + quad) ^ (row&7))*8 ; row&7 == ml&7 here.
  const int aBase = (wr * 128 + ml) * 64;
  const int bBase = (wc * 64 + ml) * 64;
  const int kc0 = ((quad     ) ^ (ml & 7)) * 8;   // ks=0
  const int kc1 = ((quad + 4 ) ^ (ml & 7)) * 8;   // ks=1

  short8 ar[4][2], br0[2][2], br1[2][2];
  f32x4 acc[8][4] = {};

#define LDA(buf, mh) do {                                                      \
    _Pragma("unroll")                                                          \
    for (int q = 0; q < 4; ++q) {                                              \
      ar[q][0] = *(const short8*)&sh[buf][0][aBase + (mh)*4096 + q*1024 + kc0];\
      ar[q][1] = *(const short8*)&sh[buf][0][aBase + (mh)*4096 + q*1024 + kc1];\
    } } while (0)

#define LDB(dst, buf, nh) do {                                                 \
    _Pragma("unroll")                                                          \
    for (int n = 0; n < 2; ++n) {                                              \
      dst[n][0] = *(const short8*)&sh[buf][1][bBase + (nh)*2048 + n*1024 + kc0];\
      dst[n][1] = *(const short8*)&sh[buf][1][bBase + (nh)*2048 + n*1024 + kc1];\
    } } while (0)

#define MM(mh, nh, BSRC) do {                                                  \
    __builtin_amdgcn_s_setprio(1);                                             \
    _Pragma("unroll")                                                          \
    for (int q = 0; q < 4; ++q)                                                \
      _Pragma("unroll")                                                        \
      for (int n = 0; n < 2; ++n)                                              \
        _Pragma("unroll")                                                      \
        for (int ks = 0; ks < 2; ++ks)                                         \
          acc[(mh)*4 + q][(nh)*2 + n] = __builtin_amdgcn_mfma_f32_16x16x32_bf16(\
              ar[q][ks], BSRC[n][ks], acc[(mh)*4 + q][(nh)*2 + n], 0, 0, 0);   \
    __builtin_amdgcn_s_setprio(0);                                             \
  } while (0)

  // ---- prologue: buf0 <- tile0 (all), buf1.B <- tile1 ----
  STG(0, 0, 0, gA, 0);   // b0.Ah0
  STG(0, 0, 1, gA, 0);   // b0.Ah1
  STG(0, 1, 0, gB, 0);   // b0.Bh0
  STG(0, 1, 1, gB, 0);   // b0.Bh1
  STG(1, 1, 0, gB, 1);   // b1.Bh0
  STG(1, 1, 1, gB, 1);   // b1.Bh1
  WAITVM(4);             // oldest 8 loads (= all of buf0) landed
  BAR();

  // ---- main loop: 8 phases / iteration, tiles (2i, 2i+1); prefetch (2i+2, 2i+3)
  // Quadrant order per tile: Q00, Q01, Q11, Q10.
  // Stage plan (overwrite- and landing-safe, vmcnt(4) at ph4 & ph8):
  //  ph1: b1.Ah0<-t1   ph2: b1.Ah1<-t1   ph3: b0.Bh0<-p0   ph4: b0.Bh1<-p0 +VM(4)
  //  ph5: b0.Ah0<-p0   ph6: b0.Ah1<-p0   ph7: b1.Bh0<-p1   ph8: b1.Bh1<-p1 +VM(4)
#pragma unroll 1
  for (int i = 0; i < 7; ++i) {
    const int t1 = 2 * i + 1, p0 = 2 * i + 2, p1 = 2 * i + 3;
    // ph1: Q00 of t0 (buf0)
    LDA(0, 0); LDB(br0, 0, 0);
    STG(1, 0, 0, gA, t1);
    BAR(); MM(0, 0, br0); BAR();
    // ph2: Q01
    LDB(br1, 0, 1);
    STG(1, 0, 1, gA, t1);
    BAR(); MM(0, 1, br1); BAR();
    // ph3: Q11
    LDA(0, 1);
    STG(0, 1, 0, gB, p0);
    BAR(); MM(1, 1, br1); BAR();
    // ph4: Q10 (no ds_reads)
    STG(0, 1, 1, gB, p0);
    WAITVM(4);                       // b1.Ah0/Ah1 (ph1/2) + prev b1.B landed
    BAR(); MM(1, 0, br0); BAR();
    // ph5: Q00 of t1 (buf1)
    LDA(1, 0); LDB(br0, 1, 0);
    STG(0, 0, 0, gA, p0);
    BAR(); MM(0, 0, br0); BAR();
    // ph6: Q01
    LDB(br1, 1, 1);
    STG(0, 0, 1, gA, p0);
    BAR(); MM(0, 1, br1); BAR();
    // ph7: Q11
    LDA(1, 1);
    STG(1, 1, 0, gB, p1);
    BAR(); MM(1, 1, br1); BAR();
    // ph8: Q10
    STG(1, 1, 1, gB, p1);
    WAITVM(4);                       // buf0 (= tile p0, staged ph3-6) landed
    BAR(); MM(1, 0, br0); BAR();
  }

  // ---- epilogue: tiles 14 (buf0), 15 (buf1) ----
  {
    // ph1
    LDA(0, 0); LDB(br0, 0, 0);
    STG(1, 0, 0, gA, 15);
    BAR(); MM(0, 0, br0); BAR();
    // ph2
    LDB(br1, 0, 1);
    STG(1, 0, 1, gA, 15);
    BAR(); MM(0, 1, br1); BAR();
    // ph3
    LDA(0, 1);
    BAR(); MM(1, 1, br1); BAR();
    // ph4
    WAITVM(0);                       // drain all of tile 15
    BAR(); MM(1, 0, br0); BAR();
    // ph5
    LDA(1, 0); LDB(br0, 1, 0);
    BAR(); MM(0, 0, br0); BAR();
    // ph6
    LDB(br1, 1, 1);
    BAR(); MM(0, 1, br1); BAR();
    // ph7
    LDA(1, 1);
    BAR(); MM(1, 1, br1); BAR();
    // ph8 (no more LDS hazards)
    MM(1, 0, br0);
  }

  // ---- C write: row = quad*4+r over A-rows, col = ml over B-rows ----
  float* Cb = C + (size_t)batch * NDIM * MDIM
                + (size_t)(trow * BM + wr * 128 + quad * 4) * MDIM
                + (tcol * BN + wc * 64 + ml);
#pragma unroll
  for (int mi = 0; mi < 8; ++mi) {
#pragma unroll
    for (int ni = 0; ni < 4; ++ni) {
      float* cp = Cb + (size_t)(mi * 16) * MDIM + ni * 16;
#pragma unroll
      for (int r = 0; r < 4; ++r)
        cp[(size_t)r * MDIM] = acc[mi][ni][r];
    }
  }
#undef STG
#undef LDA
#undef LDB
#undef MM
}

// ---------------- fallback (R1 kernel): fused fp32->bf16 staging ----------------
static constexpr int FBM = 128;
static constexpr int FBN = 128;
static constexpr int FBK = 32;
static constexpr int FKIT = EDIM / FBK;
static constexpr int LSTR = 40;

__device__ __forceinline__ unsigned pk(float lo, float hi) {
  return __builtin_amdgcn_perm(__float_as_uint(hi), __float_as_uint(lo), 0x07060302u);
}
__device__ __forceinline__ u32x4 pack8(f32x4 x, f32x4 y) {
  u32x4 r;
  r[0] = pk(x[0], x[1]); r[1] = pk(x[2], x[3]);
  r[2] = pk(y[0], y[1]); r[3] = pk(y[2], y[3]);
  return r;
}

__global__ __launch_bounds__(256, 3)
void bmm_bt_kernel(const float* __restrict__ A, const float* __restrict__ B,
                   float* __restrict__ C) {
  __shared__ u16 As[FBM * LSTR];
  __shared__ u16 Bs[FBN * LSTR];

  const int tid  = threadIdx.x;
  const int lane = tid & 63;
  const int wave = tid >> 6;
  const int quad = lane >> 4;
  const int ml   = lane & 15;
  const int wrow = (wave >> 1) * 64;
  const int wcol = (wave & 1) * 64;

  const int tcol  = blockIdx.x;
  const int trow  = blockIdx.y;
  const int batch = blockIdx.z;

  const float* Ab = A + (size_t)batch * NDIM * EDIM + (size_t)trow * FBM * EDIM;
  const float* Bb = B + (size_t)batch * MDIM * EDIM + (size_t)tcol * FBN * EDIM;
  float*       Cb = C + (size_t)batch * NDIM * MDIM;

  const int r0 = tid >> 2;
  const int p0 = (tid & 3) * 8;
  const int r1 = r0 + 64;

  const float* pA0 = Ab + (size_t)r0 * EDIM + p0;
  const float* pA1 = Ab + (size_t)r1 * EDIM + p0;
  const float* pB0 = Bb + (size_t)r0 * EDIM + p0;
  const float* pB1 = Bb + (size_t)r1 * EDIM + p0;

  u16* wA0 = &As[r0 * LSTR + p0];
  u16* wA1 = &As[r1 * LSTR + p0];
  u16* wB0 = &Bs[r0 * LSTR + p0];
  u16* wB1 = &Bs[r1 * LSTR + p0];

  f32x4 a0 = *(const f32x4*)(pA0);
  f32x4 a1 = *(const f32x4*)(pA0 + 4);
  f32x4 a2 = *(const f32x4*)(pA1);
  f32x4 a3 = *(const f32x4*)(pA1 + 4);
  f32x4 b0 = *(const f32x4*)(pB0);
  f32x4 b1 = *(const f32x4*)(pB0 + 4);
  f32x4 b2 = *(const f32x4*)(pB1);
  f32x4 b3 = *(const f32x4*)(pB1 + 4);

  f32x4 acc[4][4] = {};

  for (int kb = 0; kb < FKIT; ++kb) {
    __syncthreads();
    *(u32x4*)wA0 = pack8(a0, a1);
    *(u32x4*)wA1 = pack8(a2, a3);
    *(u32x4*)wB0 = pack8(b0, b1);
    *(u32x4*)wB1 = pack8(b2, b3);
    __syncthreads();

    if (kb + 1 < FKIT) {
      const int off = (kb + 1) * FBK;
      a0 = *(const f32x4*)(pA0 + off);
      a1 = *(const f32x4*)(pA0 + off + 4);
      a2 = *(const f32x4*)(pA1 + off);
      a3 = *(const f32x4*)(pA1 + off + 4);
      b0 = *(const f32x4*)(pB0 + off);
      b1 = *(const f32x4*)(pB0 + off + 4);
      b2 = *(const f32x4*)(pB1 + off);
      b3 = *(const f32x4*)(pB1 + off + 4);
    }

    short8 af[4], bfr[4];
#pragma unroll
    for (int i = 0; i < 4; ++i)
      af[i] = *(const short8*)&As[(wrow + i * 16 + ml) * LSTR + quad * 8];
#pragma unroll
    for (int i = 0; i < 4; ++i)
      bfr[i] = *(const short8*)&Bs[(wcol + i * 16 + ml) * LSTR + quad * 8];

#pragma unroll
    for (int mi = 0; mi < 4; ++mi)
#pragma unroll
      for (int ni = 0; ni < 4; ++ni)
        acc[mi][ni] = __builtin_amdgcn_mfma_f32_16x16x32_bf16(
            af[mi], bfr[ni], acc[mi][ni], 0, 0, 0);
  }

  const int crow = trow * FBM + wrow + quad * 4;
  const int ccol = tcol * FBN + wcol + ml;
#pragma unroll
  for (int mi = 0; mi < 4; ++mi) {
#pragma unroll
    for (int ni = 0; ni < 4; ++ni) {
      float* cp = Cb + (size_t)(crow + mi * 16) * MDIM + (ccol + ni * 16);
#pragma unroll
      for (int r = 0; r < 4; ++r)
        cp[(size_t)r * MDIM] = acc[mi][ni][r];
    }
  }
}

extern "C" void kernel_launch(void* const* d_in, const int* in_sizes, int n_in,
                              void* d_out, int out_size, void* d_ws, size_t ws_size,
                              hipStream_t stream) {
  const float* A = (const float*)d_in[0];
  const float* B = (const float*)d_in[1];
  float*       C = (float*)d_out;

  const size_t elems = (size_t)BATCH * NDIM * EDIM;      // per matrix
  const size_t need  = 2 * elems * sizeof(u16);          // 64 MiB

  if (ws_size >= need) {
    u16* Abf = (u16*)d_ws;
    u16* Bbf = Abf + elems;
    const int cvt_blocks = (int)(2 * elems / (256 * 8)); // 16384
    cvt_kernel<<<cvt_blocks, 256, 0, stream>>>(A, B, Abf, Bbf);
    dim3 grid(MDIM / BN, NDIM / BM, BATCH);              // 8 x 8 x 8
    bmm_8ph_kernel<<<grid, dim3(512), 0, stream>>>(Abf, Bbf, C);
  } else {
    dim3 grid(MDIM / FBN, NDIM / FBM, BATCH);
    bmm_bt_kernel<<<grid, dim3(256), 0, stream>>>(A, B, C);
  }
}